// Round 1
// 186.449 us; speedup vs baseline: 1.1071x; 1.1071x over previous
//
#include <hip/hip_runtime.h>
#include <math.h>

#define INV_SQRT2F 0.7071067811865476f

// Reduction-slot layout in ws (float indices).
// R0 finding: 2048 blocks all finishing simultaneously (one-shot grid) and
// atomicAdd-ing the SAME 64-B line (ws[0]/ws[1]) creates a serialized RMW
// tail at the coherence point (~40 us, visible as 40% avg occupancy and 4%
// VALUBusy). Spread the block-level atomics over 32 slots, each slot on its
// own 128-B L2 line -> contention per line drops 32x.
#define NSLOT       32
#define SLOT_STRIDE 32                               // 32 floats = 128 B line
#define S1_BASE     16
#define S2_BASE     (S1_BASE + NSLOT * SLOT_STRIDE)  // 16 + 1024
#define SE_BASE     (S2_BASE + NSLOT * SLOT_STRIDE)  // 16 + 2048
#define WS_FLOATS   (SE_BASE + NSLOT * SLOT_STRIDE)  // 3088 floats = 12352 B

// 2048 blocks x 256 threads x 8 float4/thread == n4 exactly: each thread
// issues ONE cluster of 16 independent dwordx4 loads, sched_barrier(0) pins
// all 16 loads before any consumption. launch_bounds(256,4): 128-VGPR
// budget, >=16 waves/CU.

__global__ void __launch_bounds__(256, 4)
pass_sums(const float4* __restrict__ pred4, const float4* __restrict__ targ4,
          int n4, float* __restrict__ ws) {
    const int stride = gridDim.x * blockDim.x;
    int i = blockIdx.x * blockDim.x + threadIdx.x;
    float s1 = 0.f, s2 = 0.f;

    for (; i + 7 * stride < n4; i += 8 * stride) {
        float4 p[8], t[8];
#pragma unroll
        for (int u = 0; u < 8; ++u) p[u] = pred4[i + u * stride];
#pragma unroll
        for (int u = 0; u < 8; ++u) t[u] = targ4[i + u * stride];
        __builtin_amdgcn_sched_barrier(0);   // all 16 loads issued before any use
#pragma unroll
        for (int u = 0; u < 8; ++u) {
            float d0 = fabsf(p[u].x - t[u].x);
            float d1 = fabsf(p[u].y - t[u].y);
            float d2 = fabsf(p[u].z - t[u].z);
            float d3 = fabsf(p[u].w - t[u].w);
            s1 += (d0 + d1) + (d2 + d3);
            s2 += (d0 * d0 + d1 * d1) + (d2 * d2 + d3 * d3);
        }
    }
    for (; i < n4; i += stride) {            // tail (empty at this problem size)
        float4 p = pred4[i], t = targ4[i];
        float d0 = fabsf(p.x - t.x), d1 = fabsf(p.y - t.y);
        float d2 = fabsf(p.z - t.z), d3 = fabsf(p.w - t.w);
        s1 += (d0 + d1) + (d2 + d3);
        s2 += (d0 * d0 + d1 * d1) + (d2 * d2 + d3 * d3);
    }

    for (int off = 32; off > 0; off >>= 1) {
        s1 += __shfl_down(s1, off);
        s2 += __shfl_down(s2, off);
    }
    __shared__ float ls1[4], ls2[4];
    int lane = threadIdx.x & 63;
    int wid  = threadIdx.x >> 6;
    if (lane == 0) { ls1[wid] = s1; ls2[wid] = s2; }
    __syncthreads();
    if (threadIdx.x == 0) {
        int slot = (blockIdx.x & (NSLOT - 1)) * SLOT_STRIDE;
        atomicAdd(&ws[S1_BASE + slot], (ls1[0] + ls1[1]) + (ls1[2] + ls1[3]));
        atomicAdd(&ws[S2_BASE + slot], (ls2[0] + ls2[1]) + (ls2[2] + ls2[3]));
    }
}

__global__ void __launch_bounds__(256, 4)
pass_erf(const float4* __restrict__ pred4, const float4* __restrict__ targ4,
         int n4, int n, float* __restrict__ ws) {
    // Sum the 32 per-slot partials (uniform scalar loads, L2-broadcast).
    float sum_d = 0.f, sum_d2 = 0.f;
#pragma unroll
    for (int sidx = 0; sidx < NSLOT; ++sidx) {
        sum_d  += ws[S1_BASE + sidx * SLOT_STRIDE];
        sum_d2 += ws[S2_BASE + sidx * SLOT_STRIDE];
    }
    float nf     = (float)n;
    float mean_d = sum_d / nf;
    float var    = (sum_d2 - sum_d * mean_d) / (nf - 1.0f);
    float k      = INV_SQRT2F / var;

    const int stride = gridDim.x * blockDim.x;
    int i = blockIdx.x * blockDim.x + threadIdx.x;
    float s = 0.f;

    for (; i + 7 * stride < n4; i += 8 * stride) {
        float4 p[8], t[8];
#pragma unroll
        for (int u = 0; u < 8; ++u) p[u] = pred4[i + u * stride];
#pragma unroll
        for (int u = 0; u < 8; ++u) t[u] = targ4[i + u * stride];
        __builtin_amdgcn_sched_barrier(0);
#pragma unroll
        for (int u = 0; u < 8; ++u) {
            s += (erff(fabsf(p[u].x - t[u].x) * k) + erff(fabsf(p[u].y - t[u].y) * k))
               + (erff(fabsf(p[u].z - t[u].z) * k) + erff(fabsf(p[u].w - t[u].w) * k));
        }
    }
    for (; i < n4; i += stride) {
        float4 p = pred4[i], t = targ4[i];
        s += (erff(fabsf(p.x - t.x) * k) + erff(fabsf(p.y - t.y) * k))
           + (erff(fabsf(p.z - t.z) * k) + erff(fabsf(p.w - t.w) * k));
    }

    for (int off = 32; off > 0; off >>= 1)
        s += __shfl_down(s, off);
    __shared__ float ls[4];
    int lane = threadIdx.x & 63;
    int wid  = threadIdx.x >> 6;
    if (lane == 0) ls[wid] = s;
    __syncthreads();
    if (threadIdx.x == 0) {
        int slot = (blockIdx.x & (NSLOT - 1)) * SLOT_STRIDE;
        atomicAdd(&ws[SE_BASE + slot], (ls[0] + ls[1]) + (ls[2] + ls[3]));
    }
}

__global__ void finalize(const float* __restrict__ ws, float* __restrict__ out, int n) {
    float sum_d = 0.f, sum_d2 = 0.f, sum_erf = 0.f;
#pragma unroll
    for (int sidx = 0; sidx < NSLOT; ++sidx) {
        sum_d   += ws[S1_BASE + sidx * SLOT_STRIDE];
        sum_d2  += ws[S2_BASE + sidx * SLOT_STRIDE];
        sum_erf += ws[SE_BASE + sidx * SLOT_STRIDE];
    }
    float nf      = (float)n;
    float mean_d  = sum_d / nf;
    float var     = (sum_d2 - sum_d * mean_d) / (nf - 1.0f);
    float p       = 1.0f - sum_erf / nf;          // p_correct
    float gamma   = -logf(p);
    float coef    = expf(gamma * logf(1.0f - p)); // (1-p)^gamma
    out[0] = coef * mean_d + logf(var + 1.0f);    // LOSS_WEIGHT = 1
}

extern "C" void kernel_launch(void* const* d_in, const int* in_sizes, int n_in,
                              void* d_out, int out_size, void* d_ws, size_t ws_size,
                              hipStream_t stream) {
    const float4* pred4 = (const float4*)d_in[0];
    const float4* targ4 = (const float4*)d_in[1];
    float* out = (float*)d_out;
    float* ws  = (float*)d_ws;
    int n  = in_sizes[0];        // 16777216
    int n4 = n >> 2;

    // ws re-poisoned to 0xAA before every call — zero the slot region
    hipMemsetAsync(d_ws, 0, WS_FLOATS * sizeof(float), stream);

    const int block = 256;
    const int grid  = 2048;      // 2048*256*8 float4 == n4 exactly: one-shot clusters

    pass_sums<<<grid, block, 0, stream>>>(pred4, targ4, n4, ws);
    pass_erf<<<grid, block, 0, stream>>>(pred4, targ4, n4, n, ws);
    finalize<<<1, 1, 0, stream>>>(ws, out, n);
}